// Round 5
// baseline (65.379 us; speedup 1.0000x reference)
//
#include <hip/hip_runtime.h>

// MoE gate: logits = x @ W^T (x:[16384,2048] f32, W:[64,2048] f32),
// softmax over 64 experts, top-8 -> weights f32 + indices stored as f32.
//
// R5: pack_w (W -> 32x32-B-fragment-ordered bf16 3-way-split triples, 768KB,
// L2-resident) + main: grid 256 (1 block/CU), 512 thr = 8 waves, TT=64,
// BK=64, THREE-deep LDS pipeline (counted vmcnt(10), raw s_barrier, never
// vmcnt(0) in steady state). Wave = 32tok x 32exp x K-half (2-way K-split,
// combined in LDS). mfma_f32_32x32x16_bf16, 6-product exact split ~= fp32.
// x staged row-major with granule-XOR source pre-swizzle + matching XOR on
// ds_read (both-sides swizzle, rule #21).

typedef __attribute__((ext_vector_type(8))) short short8;
typedef __attribute__((ext_vector_type(16))) float f32x16;
typedef __attribute__((ext_vector_type(4))) float f32x4;

#define NT    16384
#define DIMK  2048
#define NE    64
#define TOPKK 8
#define TT    64
#define CH    32
#define BUFB  40960                 // per-buffer: x 16KB + W 24KB
#define WS_BYTES (CH * 24 * 1024)   // 786432

union U4S8 { unsigned int u[4]; short8 s; };

// Bit-exact 3-way bf16 split of 8 f32 (truncation; subtractions exact).
__device__ __forceinline__ void split3(const float4 a, const float4 b,
                                       short8& H, short8& M, short8& L) {
    const float f[8] = {a.x, a.y, a.z, a.w, b.x, b.y, b.z, b.w};
    U4S8 uh, um, ul;
#pragma unroll
    for (int p = 0; p < 4; ++p) {
        const float f0 = f[2 * p], f1 = f[2 * p + 1];
        const unsigned int t0 = __float_as_uint(f0) & 0xFFFF0000u;
        const unsigned int t1 = __float_as_uint(f1) & 0xFFFF0000u;
        uh.u[p] = (t0 >> 16) | t1;
        const float r0 = f0 - __uint_as_float(t0);
        const float r1 = f1 - __uint_as_float(t1);
        const unsigned int v0 = __float_as_uint(r0) & 0xFFFF0000u;
        const unsigned int v1 = __float_as_uint(r1) & 0xFFFF0000u;
        um.u[p] = (v0 >> 16) | v1;
        const float s0 = r0 - __uint_as_float(v0);
        const float s1 = r1 - __uint_as_float(v1);
        ul.u[p] = (__float_as_uint(s0) >> 16) | (__float_as_uint(s1) & 0xFFFF0000u);
    }
    H = uh.s; M = um.s; L = ul.s;
}

__device__ __forceinline__ f32x16 mfma6w(short8 ah, short8 am, short8 al,
                                         short8 bh, short8 bm, short8 bl,
                                         f32x16 c) {
    c = __builtin_amdgcn_mfma_f32_32x32x16_bf16(ah, bh, c, 0, 0, 0);
    c = __builtin_amdgcn_mfma_f32_32x32x16_bf16(ah, bm, c, 0, 0, 0);
    c = __builtin_amdgcn_mfma_f32_32x32x16_bf16(am, bh, c, 0, 0, 0);
    c = __builtin_amdgcn_mfma_f32_32x32x16_bf16(ah, bl, c, 0, 0, 0);
    c = __builtin_amdgcn_mfma_f32_32x32x16_bf16(am, bm, c, 0, 0, 0);
    c = __builtin_amdgcn_mfma_f32_32x32x16_bf16(al, bh, c, 0, 0, 0);
    return c;
}

__device__ __forceinline__ void async16(void* lds, const void* gp) {
    __builtin_amdgcn_global_load_lds(
        (const __attribute__((address_space(1))) unsigned int*)gp,
        (__attribute__((address_space(3))) unsigned int*)lds, 16, 0, 0);
}

#define SCHED_FENCE() __builtin_amdgcn_sched_barrier(0)
#define VM_WAIT10() do { asm volatile("s_waitcnt vmcnt(10)" ::: "memory"); SCHED_FENCE(); } while (0)
#define VM_WAIT5()  do { asm volatile("s_waitcnt vmcnt(5)"  ::: "memory"); SCHED_FENCE(); } while (0)
#define VM_WAIT0()  do { asm volatile("s_waitcnt vmcnt(0)"  ::: "memory"); SCHED_FENCE(); } while (0)
#define BAR() do { SCHED_FENCE(); __builtin_amdgcn_s_barrier(); SCHED_FENCE(); } while (0)

// ---- pack W -> 32x32 B-fragment-ordered bf16 triples ----
// ws layout: [c(32)][F(24)][lane(64)][8 bf16], F = (2s + n32)*3 + t;
// lane l: expert = 32*n32 + (l&31), k = 64c + 16s + 8*(l>>5) + 0..7.
__global__ __launch_bounds__(64) void pack_w_kernel(
    const float* __restrict__ W, short* __restrict__ wpk)
{
    const int b  = blockIdx.x;          // 256 = c*8 + fg, fg = 2s + n32
    const int c  = b >> 3, fg = b & 7;
    const int s  = fg >> 1, n32 = fg & 1;
    const int l  = threadIdx.x;
    const float* g = W + (size_t)(32 * n32 + (l & 31)) * DIMK
                       + 64 * c + 16 * s + 8 * (l >> 5);
    const float4 lo = *(const float4*)g;
    const float4 hi = *(const float4*)(g + 4);
    short8 H, M, L;
    split3(lo, hi, H, M, L);
    const size_t base = ((size_t)(c * 8 + fg) * 3) * 512 + l * 8;
    *(short8*)(wpk + base)        = H;
    *(short8*)(wpk + base + 512)  = M;
    *(short8*)(wpk + base + 1024) = L;
}

// ---- main fused kernel ----
__global__ __launch_bounds__(512, 1) void gate_main_kernel(
    const float* __restrict__ x, const short* __restrict__ wp,
    float* __restrict__ out)
{
    extern __shared__ __align__(16) char smem[];   // 3 * 40960 = 122880

    const int tid = threadIdx.x;
    const int w   = tid >> 6;        // 8 waves
    const int l   = tid & 63;
    const int lj  = l & 15;
    const int lq  = l >> 4;
    const int l5  = l >> 5;
    const int r31 = l & 31;
    const int tg  = (w >> 2) & 1;    // token group (32 tokens)
    const int eg  = (w >> 1) & 1;    // expert group (32 experts)
    const int sph = w & 1;           // K-half within chunk
    const int bt0 = blockIdx.x * TT;

#define XB(B) (smem + (B) * BUFB)
#define WBUF(B) (smem + (B) * BUFB + 16384)

// 5 loads/wave: 2 x-instrs (4 rows x 256B contiguous source, XOR'd 16B
// granules), 3 W-instrs (1KB lane-contiguous). LDS dests linear.
#define STAGE(cc, B) do {                                                     \
    _Pragma("unroll")                                                         \
    for (int ii = 0; ii < 2; ++ii) {                                          \
        const int i = 2 * w + ii;                                             \
        const int r = 4 * i + lq;                                             \
        const float* gsrc = x + (size_t)(bt0 + r) * DIMK + (cc) * 64          \
                              + ((lj ^ (r & 7)) << 2);                        \
        async16(XB(B) + i * 1024, gsrc);                                      \
    }                                                                         \
    _Pragma("unroll")                                                         \
    for (int t = 0; t < 3; ++t) {                                             \
        const int F = 3 * w + t;                                              \
        const short* gs = wp + ((size_t)(cc) * 24 + F) * 512 + l * 8;         \
        async16(WBUF(B) + F * 1024, gs);                                      \
    }                                                                         \
} while (0)

// Wave (tg,eg,sph): A = x rows 32tg..+31, k-half sph; B = W frag (s,eg).
#define COMPUTE(B) do {                                                       \
    const char* xb = XB(B);                                                   \
    const char* wb = WBUF(B);                                                 \
    const int row = 32 * tg + r31;                                            \
    const int rx  = row & 7;                                                  \
    _Pragma("unroll")                                                         \
    for (int ks = 0; ks < 2; ++ks) {                                          \
        const int s   = 2 * sph + ks;                                         \
        const int sl0 = (4 * s + 2 * l5 + 0) ^ rx;                            \
        const int sl1 = (4 * s + 2 * l5 + 1) ^ rx;                            \
        const float4 a0 = *(const float4*)(xb + row * 256 + sl0 * 16);        \
        const float4 a1 = *(const float4*)(xb + row * 256 + sl1 * 16);        \
        short8 H, M, L;                                                       \
        split3(a0, a1, H, M, L);                                              \
        const int F = (2 * s + eg) * 3;                                       \
        const short8 bh  = *(const short8*)(wb + (F + 0) * 1024 + l * 16);    \
        const short8 bm  = *(const short8*)(wb + (F + 1) * 1024 + l * 16);    \
        const short8 bl_ = *(const short8*)(wb + (F + 2) * 1024 + l * 16);    \
        acc = mfma6w(H, M, L, bh, bm, bl_, acc);                              \
    }                                                                         \
} while (0)

    f32x16 acc;
#pragma unroll
    for (int i = 0; i < 16; ++i) acc[i] = 0.f;

    // prologue: 3 stages in flight (15 loads/wave)
    STAGE(0, 0);
    STAGE(1, 1);
    STAGE(2, 2);

#pragma unroll 1
    for (int cb = 0; cb < CH - 2; cb += 3) {
        VM_WAIT10(); BAR();          // stage(cb) landed (2 stages in flight)
        COMPUTE(0);
        BAR();                       // buf0 reads done
        STAGE(cb + 3, 0);

        VM_WAIT10(); BAR();
        COMPUTE(1);
        BAR();
        STAGE(cb + 4, 1);

        VM_WAIT10(); BAR();
        COMPUTE(2);
        BAR();
        if (cb + 5 < CH) STAGE(cb + 5, 2);
    }
    // tail: chunks 30 (buf0), 31 (buf1)
    VM_WAIT5(); BAR();
    COMPUTE(0);
    BAR();
    VM_WAIT0(); BAR();
    COMPUTE(1);
    BAR();

    // ---- partial logits -> lg[sph][64][65] (aliases buffers; reads done) --
    // C/D 32x32: col = l&31 (expert), row = (r&3) + 8*(r>>2) + 4*(l>>5).
    float* lg = (float*)smem;
#pragma unroll
    for (int r = 0; r < 16; ++r) {
        const int rowc = (r & 3) + 8 * (r >> 2) + 4 * l5;
        lg[(sph * TT + 32 * tg + rowc) * (NE + 1) + 32 * eg + r31] = acc[r];
    }
    __syncthreads();

    // ---- 2-way K-split reduction: 4096 entries / 512 threads ----
#pragma unroll
    for (int rr = 0; rr < (TT * NE) / 512; ++rr) {
        const int idx = tid + rr * 512;
        const int t = idx >> 6, e = idx & 63;
        lg[t * (NE + 1) + e] += lg[(TT + t) * (NE + 1) + e];
    }
    __syncthreads();

    // ---- fused softmax + top-8: one lane per token (wave 0) ----
    if (tid < TT) {
        const float* rowp = lg + tid * (NE + 1);
        float mx = -3.402823466e38f;
        for (int e = 0; e < NE; ++e) mx = fmaxf(mx, rowp[e]);
        float sden = 0.f;
        for (int e = 0; e < NE; ++e) sden += expf(rowp[e] - mx);

        float tv[TOPKK];
        int   ti[TOPKK];
#pragma unroll
        for (int i = 0; i < TOPKK; ++i) { tv[i] = -3.402823466e38f; ti[i] = 0; }
        for (int e = 0; e < NE; ++e) {
            const float v = rowp[e];
            if (v > tv[TOPKK - 1]) {
                tv[TOPKK - 1] = v; ti[TOPKK - 1] = e;
#pragma unroll
                for (int q = TOPKK - 1; q > 0; --q) {
                    if (tv[q] > tv[q - 1]) {
                        const float fv = tv[q]; tv[q] = tv[q - 1]; tv[q - 1] = fv;
                        const int   iv = ti[q]; ti[q] = ti[q - 1]; ti[q - 1] = iv;
                    }
                }
            }
        }
        float* ow = out + (size_t)(bt0 + tid) * TOPKK;
        float* oi = out + (size_t)NT * TOPKK + (size_t)(bt0 + tid) * TOPKK;
#pragma unroll
        for (int i = 0; i < TOPKK; ++i) {
            ow[i] = expf(tv[i] - mx) / sden;   // ROUTE_SCALE == 1.0
            oi[i] = (float)ti[i];
        }
    }
#undef STAGE
#undef COMPUTE
#undef XB
#undef WBUF
}

// ================= fallback (R2 kernel) if ws too small =================
__device__ __forceinline__ f32x4 mfma6s(short8 ah, short8 am, short8 al,
                                        short8 bh, short8 bm, short8 bl, f32x4 c) {
    c = __builtin_amdgcn_mfma_f32_16x16x32_bf16(ah, bh, c, 0, 0, 0);
    c = __builtin_amdgcn_mfma_f32_16x16x32_bf16(ah, bm, c, 0, 0, 0);
    c = __builtin_amdgcn_mfma_f32_16x16x32_bf16(am, bh, c, 0, 0, 0);
    c = __builtin_amdgcn_mfma_f32_16x16x32_bf16(ah, bl, c, 0, 0, 0);
    c = __builtin_amdgcn_mfma_f32_16x16x32_bf16(am, bm, c, 0, 0, 0);
    c = __builtin_amdgcn_mfma_f32_16x16x32_bf16(al, bh, c, 0, 0, 0);
    return c;
}

__device__ __forceinline__ void load_step(const float* xp0, const float* xp1,
                                          const float* wp, int koff,
                                          float4 xb[2][2], float4 wb[4][2]) {
#pragma unroll
    for (int h = 0; h < 2; ++h) {
        xb[0][h] = *(const float4*)(xp0 + koff + 4 * h);
        xb[1][h] = *(const float4*)(xp1 + koff + 4 * h);
    }
#pragma unroll
    for (int n = 0; n < 4; ++n)
#pragma unroll
        for (int h = 0; h < 2; ++h)
            wb[n][h] = *(const float4*)(wp + (size_t)n * 16 * DIMK + koff + 4 * h);
}

__device__ __forceinline__ void do_step(const float4 xc[2][2], const float4 wc[4][2],
                                        f32x4 acc[2][4]) {
    short8 ah[2], am[2], al[2];
#pragma unroll
    for (int m = 0; m < 2; ++m) split3(xc[m][0], xc[m][1], ah[m], am[m], al[m]);
#pragma unroll
    for (int n = 0; n < 4; ++n) {
        short8 bh, bm, bl;
        split3(wc[n][0], wc[n][1], bh, bm, bl);
#pragma unroll
        for (int m = 0; m < 2; ++m)
            acc[m][n] = mfma6s(ah[m], am[m], al[m], bh, bm, bl, acc[m][n]);
    }
}

__global__ __launch_bounds__(256, 2) void gate_fallback_kernel(
    const float* __restrict__ x, const float* __restrict__ W,
    float* __restrict__ out)
{
    __shared__ float lg[4][32][NE + 1];
    const int tid = threadIdx.x;
    const int w = tid >> 6, l = tid & 63;
    const int j = l & 15, g = l >> 4;
    const int bt0 = blockIdx.x * 32;
    const int kb = w * 512;
    const float* xp0 = x + (size_t)(bt0 + j) * DIMK + kb + 8 * g;
    const float* xp1 = xp0 + (size_t)16 * DIMK;
    const float* wpp = W + (size_t)j * DIMK + kb + 8 * g;
    f32x4 acc[2][4];
#pragma unroll
    for (int m = 0; m < 2; ++m)
#pragma unroll
        for (int n = 0; n < 4; ++n) acc[m][n] = (f32x4){0.f, 0.f, 0.f, 0.f};
    float4 xA[2][2], wA[4][2], xB[2][2], wB[4][2];
    load_step(xp0, xp1, wpp, 0, xA, wA);
#pragma unroll 1
    for (int s = 0; s < 16; s += 2) {
        load_step(xp0, xp1, wpp, 32 * (s + 1), xB, wB);
        do_step(xA, wA, acc);
        if (s + 2 < 16) load_step(xp0, xp1, wpp, 32 * (s + 2), xA, wA);
        do_step(xB, wB, acc);
    }
#pragma unroll
    for (int m = 0; m < 2; ++m)
#pragma unroll
        for (int n = 0; n < 4; ++n)
#pragma unroll
            for (int q = 0; q < 4; ++q)
                lg[w][16 * m + 4 * g + q][16 * n + j] = acc[m][n][q];
    __syncthreads();
#pragma unroll
    for (int r = 0; r < 8; ++r) {
        const int idx = tid + r * 256;
        const int t = idx >> 6, e = idx & 63;
        lg[0][t][e] += lg[1][t][e] + lg[2][t][e] + lg[3][t][e];
    }
    __syncthreads();
    if (tid < 32) {
        const float* rowp = &lg[0][tid][0];
        float mx = -3.402823466e38f;
        for (int e = 0; e < NE; ++e) mx = fmaxf(mx, rowp[e]);
        float sden = 0.f;
        for (int e = 0; e < NE; ++e) sden += expf(rowp[e] - mx);
        float tv[TOPKK]; int ti[TOPKK];
#pragma unroll
        for (int i = 0; i < TOPKK; ++i) { tv[i] = -3.402823466e38f; ti[i] = 0; }
        for (int e = 0; e < NE; ++e) {
            const float v = rowp[e];
            if (v > tv[TOPKK - 1]) {
                tv[TOPKK - 1] = v; ti[TOPKK - 1] = e;
#pragma unroll
                for (int q = TOPKK - 1; q > 0; --q)
                    if (tv[q] > tv[q - 1]) {
                        const float fv = tv[q]; tv[q] = tv[q - 1]; tv[q - 1] = fv;
                        const int iv = ti[q]; ti[q] = ti[q - 1]; ti[q - 1] = iv;
                    }
            }
        }
        float* ow = out + (size_t)(bt0 + tid) * TOPKK;
        float* oi = out + (size_t)NT * TOPKK + (size_t)(bt0 + tid) * TOPKK;
#pragma unroll
        for (int i = 0; i < TOPKK; ++i) {
            ow[i] = expf(tv[i] - mx) / sden;
            oi[i] = (float)ti[i];
        }
    }
}

extern "C" void kernel_launch(void* const* d_in, const int* in_sizes, int n_in,
                              void* d_out, int out_size, void* d_ws, size_t ws_size,
                              hipStream_t stream) {
    const float* x = (const float*)d_in[0];
    const float* W = (const float*)d_in[1];
    float* out = (float*)d_out;
    if (ws_size >= (size_t)WS_BYTES) {
        short* wpk = (short*)d_ws;
        hipLaunchKernelGGL(pack_w_kernel, dim3(256), dim3(64), 0, stream, W, wpk);
        hipLaunchKernelGGL(gate_main_kernel, dim3(NT / TT), dim3(512),
                           3 * BUFB, stream, x, wpk, out);
    } else {
        hipLaunchKernelGGL(gate_fallback_kernel, dim3(NT / 32), dim3(256), 0, stream,
                           x, W, out);
    }
}

// Round 7
// 62.373 us; speedup vs baseline: 1.0482x; 1.0482x over previous
//
#include <hip/hip_runtime.h>

// MoE gate: logits = x @ W^T (x:[16384,2048] f32, W:[64,2048] f32),
// softmax over 64 experts, top-8 -> weights f32 + indices stored as f32.
//
// R7 (= R6 + compile fix): barrier-free register GEMM. pack_w -> bf16 H/M/L
// fragment triples (768KB, L2-hot). Main: 512 blocks x 512 thr (8 waves);
// each wave is an independent 32tok x 64exp x K/8 tile, acc in registers,
// NO barriers/LDS in the K-loop. Inline-asm global_load_dwordx4 + counted
// per-wave vmcnt (x depth-3, W depth-1.5), fully unrolled (all waits are
// literal constants; FIFO-audited). One end-barrier: 8-partial fp32 combine
// in LDS + fused softmax/top-8. mfma_f32_32x32x16_bf16, 6-product exact
// split ~= fp32 (A/B/C layouts HW-verified in R5).

typedef __attribute__((ext_vector_type(8))) short short8;
typedef __attribute__((ext_vector_type(16))) float f32x16;
typedef __attribute__((ext_vector_type(4))) float f32x4;
typedef __attribute__((ext_vector_type(4))) unsigned int u32x4;

#define NT    16384
#define DIMK  2048
#define NE    64
#define TOPKK 8
#define TT    32
#define WS_BYTES (32 * 24 * 1024)   // 786432

union U4S8 { unsigned int u[4]; short8 s; u32x4 v; };

__device__ __forceinline__ short8 as_s8(u32x4 v) { U4S8 t; t.v = v; return t.s; }

// Bit-exact 3-way bf16 split of 8 f32 (truncation; subtractions exact).
__device__ __forceinline__ void split3(const float4 a, const float4 b,
                                       short8& H, short8& M, short8& L) {
    const float f[8] = {a.x, a.y, a.z, a.w, b.x, b.y, b.z, b.w};
    U4S8 uh, um, ul;
#pragma unroll
    for (int p = 0; p < 4; ++p) {
        const float f0 = f[2 * p], f1 = f[2 * p + 1];
        const unsigned int t0 = __float_as_uint(f0) & 0xFFFF0000u;
        const unsigned int t1 = __float_as_uint(f1) & 0xFFFF0000u;
        uh.u[p] = (t0 >> 16) | t1;
        const float r0 = f0 - __uint_as_float(t0);
        const float r1 = f1 - __uint_as_float(t1);
        const unsigned int v0 = __float_as_uint(r0) & 0xFFFF0000u;
        const unsigned int v1 = __float_as_uint(r1) & 0xFFFF0000u;
        um.u[p] = (v0 >> 16) | v1;
        const float s0 = r0 - __uint_as_float(v0);
        const float s1 = r1 - __uint_as_float(v1);
        ul.u[p] = (__float_as_uint(s0) >> 16) | (__float_as_uint(s1) & 0xFFFF0000u);
    }
    H = uh.s; M = um.s; L = ul.s;
}

__device__ __forceinline__ f32x16 mfma6w(short8 ah, short8 am, short8 al,
                                         short8 bh, short8 bm, short8 bl,
                                         f32x16 c) {
    c = __builtin_amdgcn_mfma_f32_32x32x16_bf16(ah, bh, c, 0, 0, 0);
    c = __builtin_amdgcn_mfma_f32_32x32x16_bf16(ah, bm, c, 0, 0, 0);
    c = __builtin_amdgcn_mfma_f32_32x32x16_bf16(am, bh, c, 0, 0, 0);
    c = __builtin_amdgcn_mfma_f32_32x32x16_bf16(ah, bl, c, 0, 0, 0);
    c = __builtin_amdgcn_mfma_f32_32x32x16_bf16(am, bm, c, 0, 0, 0);
    c = __builtin_amdgcn_mfma_f32_32x32x16_bf16(al, bh, c, 0, 0, 0);
    return c;
}

// ---- pack W -> 32x32 B-fragment-ordered bf16 triples (verified R5) ----
// ws: [c(32)][F(24)][lane(64)][8 bf16], F = (2s + n32)*3 + t;
// lane l: expert = 32*n32 + (l&31), k = 64c + 16s + 8*(l>>5) + 0..7.
__global__ __launch_bounds__(64) void pack_w_kernel(
    const float* __restrict__ W, short* __restrict__ wpk)
{
    const int b  = blockIdx.x;          // 256 = c*8 + fg, fg = 2s + n32
    const int c  = b >> 3, fg = b & 7;
    const int s  = fg >> 1, n32 = fg & 1;
    const int l  = threadIdx.x;
    const float* g = W + (size_t)(32 * n32 + (l & 31)) * DIMK
                       + 64 * c + 16 * s + 8 * (l >> 5);
    const float4 lo = *(const float4*)g;
    const float4 hi = *(const float4*)(g + 4);
    short8 H, M, L;
    split3(lo, hi, H, M, L);
    const size_t base = ((size_t)(c * 8 + fg) * 3) * 512 + l * 8;
    *(short8*)(wpk + base)        = H;
    *(short8*)(wpk + base + 512)  = M;
    *(short8*)(wpk + base + 1024) = L;
}

// Inline-asm loads: issue only; completion ordered by manual counted vmcnt.
#define XLOADP(d0, d1, p)                                                     \
    asm volatile("global_load_dwordx4 %0, %2, off\n\t"                        \
                 "global_load_dwordx4 %1, %2, off offset:16"                  \
                 : "=&v"(d0), "=&v"(d1) : "v"(p))
#define WLOAD3(d0, d1, d2, p)                                                 \
    asm volatile("global_load_dwordx4 %0, %3, off\n\t"                        \
                 "global_load_dwordx4 %1, %3, off offset:1024\n\t"            \
                 "global_load_dwordx4 %2, %3, off offset:2048"                \
                 : "=&v"(d0), "=&v"(d1), "=&v"(d2) : "v"(p))
#define WAITN(n) do {                                                         \
    asm volatile("s_waitcnt vmcnt(" #n ")");                                  \
    __builtin_amdgcn_sched_barrier(0);                                        \
} while (0)

// ---- main fused kernel ----
__global__ __launch_bounds__(512, 2) void gate_main_kernel(
    const float* __restrict__ x, const short* __restrict__ wpk,
    float* __restrict__ out)
{
    __shared__ float lg[8][TT][NE + 1];   // 66.6 KB (combine + epilogue only)

    const int tid = threadIdx.x;
    const int w   = tid >> 6;       // wave = K-split slice id (k in [256w, 256w+256))
    const int l   = tid & 63;
    const int r31 = l & 31;
    const int l5  = l >> 5;
    const int bt0 = blockIdx.x * TT;

    // A-frag source: lane l -> token row bt0+r31, k = 256w + 8*l5 + slice*16
    const float* xp = x + (size_t)(bt0 + r31) * DIMK + w * 256 + l5 * 8;
    // W-frag sources (packed): wave chunk base c0 = 4w; advance 6144B/slice.
    const short* wq0 = wpk + (size_t)w * 49152 + l * 8;   // n32=0 triple
    const short* wq1 = wq0 + 1536;                        // n32=1 triple (+3072B)

    f32x16 acc0, acc1;
#pragma unroll
    for (int i = 0; i < 16; ++i) { acc0[i] = 0.f; acc1[i] = 0.f; }

    float4 xv[4][2];
    u32x4  w0v[2][3], w1v[2][3];

    // prologue: x(0..2), w0(0), w1(0)  [12 loads in flight]
    XLOADP(xv[0][0], xv[0][1], xp); xp += 16;
    XLOADP(xv[1][0], xv[1][1], xp); xp += 16;
    XLOADP(xv[2][0], xv[2][1], xp); xp += 16;
    WLOAD3(w0v[0][0], w0v[0][1], w0v[0][2], wq0); wq0 += 3072;
    WLOAD3(w1v[0][0], w1v[0][1], w1v[0][2], wq1); wq1 += 3072;

#pragma unroll
    for (int j = 0; j < 16; ++j) {
        const int jb = j & 3;            // x consume slot
        const int jn = (j + 1) & 1;      // W issue slot
        const int jc = j & 1;            // W consume slot
        if (j <= 12) {                   // x depth-3
            XLOADP(xv[(j + 3) & 3][0], xv[(j + 3) & 3][1], xp); xp += 16;
        }
        if (j <= 14) {                   // w0 depth-1
            WLOAD3(w0v[jn][0], w0v[jn][1], w0v[jn][2], wq0); wq0 += 3072;
        }
        // wait 1: x(j) and w0(j) landed (FIFO-audited literal counts)
        if (j <= 12)      WAITN(8);
        else if (j <= 14) WAITN(6);
        else              WAITN(3);

        short8 H, M, L;
        split3(xv[jb][0], xv[jb][1], H, M, L);
        acc0 = mfma6w(H, M, L, as_s8(w0v[jc][0]), as_s8(w0v[jc][1]),
                      as_s8(w0v[jc][2]), acc0);

        if (j <= 14) {                   // w1 depth-1
            WLOAD3(w1v[jn][0], w1v[jn][1], w1v[jn][2], wq1); wq1 += 3072;
        }
        // wait 2: w1(j) landed
        if (j <= 12)      WAITN(8);
        else if (j <= 14) WAITN(6);
        else              WAITN(0);

        acc1 = mfma6w(H, M, L, as_s8(w1v[jc][0]), as_s8(w1v[jc][1]),
                      as_s8(w1v[jc][2]), acc1);
    }

    // ---- partials -> lg[w]; C/D 32x32: col=l&31, row=(r&3)+8*(r>>2)+4*l5 --
#pragma unroll
    for (int r = 0; r < 16; ++r) {
        const int rowc = (r & 3) + 8 * (r >> 2) + 4 * l5;
        lg[w][rowc][r31]      = acc0[r];
        lg[w][rowc][32 + r31] = acc1[r];
    }
    __syncthreads();

    // ---- deterministic 8-way K-split reduction: 2048 entries / 512 thr ----
#pragma unroll
    for (int rr = 0; rr < (TT * NE) / 512; ++rr) {
        const int idx = tid + rr * 512;
        const int t = idx >> 6, e = idx & 63;
        lg[0][t][e] = ((lg[0][t][e] + lg[1][t][e]) + (lg[2][t][e] + lg[3][t][e]))
                    + ((lg[4][t][e] + lg[5][t][e]) + (lg[6][t][e] + lg[7][t][e]));
    }
    __syncthreads();

    // ---- fused softmax + top-8: one lane per token ----
    if (tid < TT) {
        const float* rowp = &lg[0][tid][0];
        float mx = -3.402823466e38f;
        for (int e = 0; e < NE; ++e) mx = fmaxf(mx, rowp[e]);
        float sden = 0.f;
        for (int e = 0; e < NE; ++e) sden += expf(rowp[e] - mx);

        float tv[TOPKK];
        int   ti[TOPKK];
#pragma unroll
        for (int i = 0; i < TOPKK; ++i) { tv[i] = -3.402823466e38f; ti[i] = 0; }
        for (int e = 0; e < NE; ++e) {
            const float v = rowp[e];
            if (v > tv[TOPKK - 1]) {
                tv[TOPKK - 1] = v; ti[TOPKK - 1] = e;
#pragma unroll
                for (int q = TOPKK - 1; q > 0; --q) {
                    if (tv[q] > tv[q - 1]) {
                        const float fv = tv[q]; tv[q] = tv[q - 1]; tv[q - 1] = fv;
                        const int   iv = ti[q]; ti[q] = ti[q - 1]; ti[q - 1] = iv;
                    }
                }
            }
        }
        float* ow = out + (size_t)(bt0 + tid) * TOPKK;
        float* oi = out + (size_t)NT * TOPKK + (size_t)(bt0 + tid) * TOPKK;
#pragma unroll
        for (int i = 0; i < TOPKK; ++i) {
            ow[i] = expf(tv[i] - mx) / sden;   // ROUTE_SCALE == 1.0
            oi[i] = (float)ti[i];
        }
    }
}

// ================= fallback (R2 kernel) if ws too small =================
__device__ __forceinline__ f32x4 mfma6s(short8 ah, short8 am, short8 al,
                                        short8 bh, short8 bm, short8 bl, f32x4 c) {
    c = __builtin_amdgcn_mfma_f32_16x16x32_bf16(ah, bh, c, 0, 0, 0);
    c = __builtin_amdgcn_mfma_f32_16x16x32_bf16(ah, bm, c, 0, 0, 0);
    c = __builtin_amdgcn_mfma_f32_16x16x32_bf16(am, bh, c, 0, 0, 0);
    c = __builtin_amdgcn_mfma_f32_16x16x32_bf16(ah, bl, c, 0, 0, 0);
    c = __builtin_amdgcn_mfma_f32_16x16x32_bf16(am, bm, c, 0, 0, 0);
    c = __builtin_amdgcn_mfma_f32_16x16x32_bf16(al, bh, c, 0, 0, 0);
    return c;
}

__device__ __forceinline__ void load_step(const float* xp0, const float* xp1,
                                          const float* wp, int koff,
                                          float4 xb[2][2], float4 wb[4][2]) {
#pragma unroll
    for (int h = 0; h < 2; ++h) {
        xb[0][h] = *(const float4*)(xp0 + koff + 4 * h);
        xb[1][h] = *(const float4*)(xp1 + koff + 4 * h);
    }
#pragma unroll
    for (int n = 0; n < 4; ++n)
#pragma unroll
        for (int h = 0; h < 2; ++h)
            wb[n][h] = *(const float4*)(wp + (size_t)n * 16 * DIMK + koff + 4 * h);
}

__device__ __forceinline__ void do_step(const float4 xc[2][2], const float4 wc[4][2],
                                        f32x4 acc[2][4]) {
    short8 ah[2], am[2], al[2];
#pragma unroll
    for (int m = 0; m < 2; ++m) split3(xc[m][0], xc[m][1], ah[m], am[m], al[m]);
#pragma unroll
    for (int n = 0; n < 4; ++n) {
        short8 bh, bm, bl;
        split3(wc[n][0], wc[n][1], bh, bm, bl);
#pragma unroll
        for (int m = 0; m < 2; ++m)
            acc[m][n] = mfma6s(ah[m], am[m], al[m], bh, bm, bl, acc[m][n]);
    }
}

__global__ __launch_bounds__(256, 2) void gate_fallback_kernel(
    const float* __restrict__ x, const float* __restrict__ W,
    float* __restrict__ out)
{
    __shared__ float lg[4][32][NE + 1];
    const int tid = threadIdx.x;
    const int w = tid >> 6, l = tid & 63;
    const int j = l & 15, g = l >> 4;
    const int bt0 = blockIdx.x * 32;
    const int kb = w * 512;
    const float* xp0 = x + (size_t)(bt0 + j) * DIMK + kb + 8 * g;
    const float* xp1 = xp0 + (size_t)16 * DIMK;
    const float* wpp = W + (size_t)j * DIMK + kb + 8 * g;
    f32x4 acc[2][4];
#pragma unroll
    for (int m = 0; m < 2; ++m)
#pragma unroll
        for (int n = 0; n < 4; ++n) acc[m][n] = (f32x4){0.f, 0.f, 0.f, 0.f};
    float4 xA[2][2], wA[4][2], xB[2][2], wB[4][2];
    load_step(xp0, xp1, wpp, 0, xA, wA);
#pragma unroll 1
    for (int s = 0; s < 16; s += 2) {
        load_step(xp0, xp1, wpp, 32 * (s + 1), xB, wB);
        do_step(xA, wA, acc);
        if (s + 2 < 16) load_step(xp0, xp1, wpp, 32 * (s + 2), xA, wA);
        do_step(xB, wB, acc);
    }
#pragma unroll
    for (int m = 0; m < 2; ++m)
#pragma unroll
        for (int n = 0; n < 4; ++n)
#pragma unroll
            for (int q = 0; q < 4; ++q)
                lg[w][16 * m + 4 * g + q][16 * n + j] = acc[m][n][q];
    __syncthreads();
#pragma unroll
    for (int r = 0; r < 8; ++r) {
        const int idx = tid + r * 256;
        const int t = idx >> 6, e = idx & 63;
        lg[0][t][e] += lg[1][t][e] + lg[2][t][e] + lg[3][t][e];
    }
    __syncthreads();
    if (tid < 32) {
        const float* rowp = &lg[0][tid][0];
        float mx = -3.402823466e38f;
        for (int e = 0; e < NE; ++e) mx = fmaxf(mx, rowp[e]);
        float sden = 0.f;
        for (int e = 0; e < NE; ++e) sden += expf(rowp[e] - mx);
        float tv[TOPKK]; int ti[TOPKK];
#pragma unroll
        for (int i = 0; i < TOPKK; ++i) { tv[i] = -3.402823466e38f; ti[i] = 0; }
        for (int e = 0; e < NE; ++e) {
            const float v = rowp[e];
            if (v > tv[TOPKK - 1]) {
                tv[TOPKK - 1] = v; ti[TOPKK - 1] = e;
#pragma unroll
                for (int q = TOPKK - 1; q > 0; --q)
                    if (tv[q] > tv[q - 1]) {
                        const float fv = tv[q]; tv[q] = tv[q - 1]; tv[q - 1] = fv;
                        const int iv = ti[q]; ti[q] = ti[q - 1]; ti[q - 1] = iv;
                    }
            }
        }
        float* ow = out + (size_t)(bt0 + tid) * TOPKK;
        float* oi = out + (size_t)NT * TOPKK + (size_t)(bt0 + tid) * TOPKK;
#pragma unroll
        for (int i = 0; i < TOPKK; ++i) {
            ow[i] = expf(tv[i] - mx) / sden;
            oi[i] = (float)ti[i];
        }
    }
}

extern "C" void kernel_launch(void* const* d_in, const int* in_sizes, int n_in,
                              void* d_out, int out_size, void* d_ws, size_t ws_size,
                              hipStream_t stream) {
    const float* x = (const float*)d_in[0];
    const float* W = (const float*)d_in[1];
    float* out = (float*)d_out;
    if (ws_size >= (size_t)WS_BYTES) {
        short* wpk = (short*)d_ws;
        hipLaunchKernelGGL(pack_w_kernel, dim3(256), dim3(64), 0, stream, W, wpk);
        hipLaunchKernelGGL(gate_main_kernel, dim3(NT / TT), dim3(512), 0, stream,
                           x, wpk, out);
    } else {
        hipLaunchKernelGGL(gate_fallback_kernel, dim3(NT / 32), dim3(256), 0, stream,
                           x, W, out);
    }
}

// Round 8
// 51.636 us; speedup vs baseline: 1.2661x; 1.2079x over previous
//
#include <hip/hip_runtime.h>

// MoE gate: logits = x @ W^T (x:[16384,2048] f32, W:[64,2048] f32),
// softmax over 64 experts, top-8 -> weights f32 + indices stored as f32.
//
// R8: barrier-free reg GEMM + wave-private LDS x-staging.
//  - grid 256 (1 block/CU), 512 thr = 8 waves; wave = 32tok x 64exp x K/4.
//  - x: 3-deep wave-private LDS chunks (32tok x 32k = 4KB), staged with 4
//    contiguous global_load_lds (128B runs), granule-XOR pre-swizzled source
//    + matching XOR ds_read (2-way banks = free). NO s_barrier in K-loop.
//  - W: packed bf16 H/M/L triples (768KB, L2-hot), register depth-3 slices
//    (4 banks) so W-waits never drain young x stages (FIFO-audited literal
//    vmcnt per slice).
//  - TT=64 halves W traffic vs R7 (total vmem 324MB).
//  - mfma_f32_32x32x16_bf16, 6-product exact split ~= fp32 (HW-verified).

typedef __attribute__((ext_vector_type(8))) short short8;
typedef __attribute__((ext_vector_type(16))) float f32x16;
typedef __attribute__((ext_vector_type(4))) float f32x4;
typedef __attribute__((ext_vector_type(4))) unsigned int u32x4;

#define NT    16384
#define DIMK  2048
#define NE    64
#define TOPKK 8
#define TT    64
#define WS_BYTES (32 * 24 * 1024)   // 786432

union U4S8 { unsigned int u[4]; short8 s; u32x4 v; };

__device__ __forceinline__ short8 as_s8(u32x4 v) { U4S8 t; t.v = v; return t.s; }

// Bit-exact 3-way bf16 split of 8 f32 (truncation; subtractions exact).
__device__ __forceinline__ void split3(const float4 a, const float4 b,
                                       short8& H, short8& M, short8& L) {
    const float f[8] = {a.x, a.y, a.z, a.w, b.x, b.y, b.z, b.w};
    U4S8 uh, um, ul;
#pragma unroll
    for (int p = 0; p < 4; ++p) {
        const float f0 = f[2 * p], f1 = f[2 * p + 1];
        const unsigned int t0 = __float_as_uint(f0) & 0xFFFF0000u;
        const unsigned int t1 = __float_as_uint(f1) & 0xFFFF0000u;
        uh.u[p] = (t0 >> 16) | t1;
        const float r0 = f0 - __uint_as_float(t0);
        const float r1 = f1 - __uint_as_float(t1);
        const unsigned int v0 = __float_as_uint(r0) & 0xFFFF0000u;
        const unsigned int v1 = __float_as_uint(r1) & 0xFFFF0000u;
        um.u[p] = (v0 >> 16) | v1;
        const float s0 = r0 - __uint_as_float(v0);
        const float s1 = r1 - __uint_as_float(v1);
        ul.u[p] = (__float_as_uint(s0) >> 16) | (__float_as_uint(s1) & 0xFFFF0000u);
    }
    H = uh.s; M = um.s; L = ul.s;
}

__device__ __forceinline__ f32x16 mfma6w(short8 ah, short8 am, short8 al,
                                         short8 bh, short8 bm, short8 bl,
                                         f32x16 c) {
    c = __builtin_amdgcn_mfma_f32_32x32x16_bf16(ah, bh, c, 0, 0, 0);
    c = __builtin_amdgcn_mfma_f32_32x32x16_bf16(ah, bm, c, 0, 0, 0);
    c = __builtin_amdgcn_mfma_f32_32x32x16_bf16(am, bh, c, 0, 0, 0);
    c = __builtin_amdgcn_mfma_f32_32x32x16_bf16(ah, bl, c, 0, 0, 0);
    c = __builtin_amdgcn_mfma_f32_32x32x16_bf16(am, bm, c, 0, 0, 0);
    c = __builtin_amdgcn_mfma_f32_32x32x16_bf16(al, bh, c, 0, 0, 0);
    return c;
}

// ---- pack W -> 32x32 B-fragment-ordered bf16 triples (verified R5/R7) ----
// ws: [c64(32)][fg(8)][t(3)][512 shorts]; fg = 2*s16 + n32;
// lane l: expert = 32*n32 + (l&31), k = 64c + 16*s16 + 8*(l>>5) + 0..7.
__global__ __launch_bounds__(64) void pack_w_kernel(
    const float* __restrict__ W, short* __restrict__ wpk)
{
    const int b  = blockIdx.x;          // 256 = c*8 + fg
    const int c  = b >> 3, fg = b & 7;
    const int s  = fg >> 1, n32 = fg & 1;
    const int l  = threadIdx.x;
    const float* g = W + (size_t)(32 * n32 + (l & 31)) * DIMK
                       + 64 * c + 16 * s + 8 * (l >> 5);
    const float4 lo = *(const float4*)g;
    const float4 hi = *(const float4*)(g + 4);
    short8 H, M, L;
    split3(lo, hi, H, M, L);
    const size_t base = ((size_t)(c * 8 + fg) * 3) * 512 + l * 8;
    *(short8*)(wpk + base)        = H;
    *(short8*)(wpk + base + 512)  = M;
    *(short8*)(wpk + base + 1024) = L;
}

// Inline-asm W loads: issue only; ordering by manual counted vmcnt.
#define WLOAD3(d0, d1, d2, p)                                                 \
    asm volatile("global_load_dwordx4 %0, %3, off\n\t"                        \
                 "global_load_dwordx4 %1, %3, off offset:1024\n\t"            \
                 "global_load_dwordx4 %2, %3, off offset:2048"                \
                 : "=&v"(d0), "=&v"(d1), "=&v"(d2) : "v"(p))
#define WAITN(n) do {                                                         \
    asm volatile("s_waitcnt vmcnt(" #n ")" ::: "memory");                     \
    __builtin_amdgcn_sched_barrier(0);                                        \
} while (0)

__device__ __forceinline__ void async16(void* lds, const void* gp) {
    __builtin_amdgcn_global_load_lds(
        (const __attribute__((address_space(1))) unsigned int*)gp,
        (__attribute__((address_space(3))) unsigned int*)lds, 16, 0, 0);
}

// ---- main fused kernel ----
__global__ __launch_bounds__(512, 1) void gate_main_kernel(
    const float* __restrict__ x, const short* __restrict__ wpk,
    float* __restrict__ out)
{
    // 8 waves x 3 bufs x 4KB = 96KB private staging; epilogue lg aliases it.
    __shared__ __align__(16) char smem[8 * 3 * 4096];

    const int tid = threadIdx.x;
    const int w   = tid >> 6;       // 8 waves
    const int l   = tid & 63;
    const int r31 = l & 31;
    const int l5  = l >> 5;
    const int tw  = w & 1;          // token half (32 tokens)
    const int kq  = w >> 2 >= 0 ? (w >> 1) : 0;  // K quarter 0..3
    const int bt0 = blockIdx.x * TT;

    char* wbase = smem + w * 12288;
    // read-side swizzle: SW(r) = (r&7) ^ (((r>>3)&3)<<1)
    const int swr = (r31 & 7) ^ (((r31 >> 3) & 3) << 1);

    // x stage source pieces: instr i covers rows 8i..8i+3? (8 rows x 128B),
    // lane l -> row_local = 8i + (l>>3), granule = (l&7) ^ (l>>3) ^ (2i).
    const int srow = l >> 3;
    const int sg0  = (l & 7) ^ srow;   // ^ (2i) added per instr
    const float* xrow0 = x + (size_t)(bt0 + 32 * tw + srow) * DIMK + kq * 512;

#define STAGE_CHUNK(k) do {                                                   \
    _Pragma("unroll")                                                         \
    for (int i = 0; i < 4; ++i) {                                             \
        const float* gsrc = xrow0 + (size_t)(8 * i) * DIMK + (k) * 32         \
                          + ((sg0 ^ (2 * i)) << 2);                           \
        async16(wbase + ((k) % 3) * 4096 + i * 1024, gsrc);                   \
    }                                                                         \
} while (0)

    // W fragment pointers (packed, L2-hot): advance 3072 shorts per 16k slice
    const short* wq0 = wpk + (size_t)kq * 98304 + l * 8;   // n32=0 triple
    const short* wq1 = wq0 + 1536;                          // n32=1 triple

    f32x16 acc0, acc1;
#pragma unroll
    for (int i = 0; i < 16; ++i) { acc0[i] = 0.f; acc1[i] = 0.f; }

    u32x4 w0v[4][3], w1v[4][3];   // depth-3 slices, 4 banks (WAR-safe)

    // ---- prologue: st0, st1, st2, W0, W1, W2 ----
    STAGE_CHUNK(0);
    STAGE_CHUNK(1);
    STAGE_CHUNK(2);
    WLOAD3(w0v[0][0], w0v[0][1], w0v[0][2], wq0); wq0 += 3072;
    WLOAD3(w1v[0][0], w1v[0][1], w1v[0][2], wq1); wq1 += 3072;
    WLOAD3(w0v[1][0], w0v[1][1], w0v[1][2], wq0); wq0 += 3072;
    WLOAD3(w1v[1][0], w1v[1][1], w1v[1][2], wq1); wq1 += 3072;
    WLOAD3(w0v[2][0], w0v[2][1], w0v[2][2], wq0); wq0 += 3072;
    WLOAD3(w1v[2][0], w1v[2][1], w1v[2][2], wq1); wq1 += 3072;

    // ---- 32 slices, fully unrolled; FIFO-audited literal waits ----
    // slice t: [issue W(t+3)] [WAIT_t] [compute t] [if odd t<=25: stage]
#define SLICE(t) do {                                                         \
    if ((t) <= 28) {                                                          \
        WLOAD3(w0v[((t)+3)&3][0], w0v[((t)+3)&3][1], w0v[((t)+3)&3][2], wq0); \
        wq0 += 3072;                                                          \
        WLOAD3(w1v[((t)+3)&3][0], w1v[((t)+3)&3][1], w1v[((t)+3)&3][2], wq1); \
        wq1 += 3072;                                                          \
    }                                                                         \
    if ((t) <= 1)            WAITN(18);                                       \
    else if ((t) == 29)      WAITN(12);                                       \
    else if ((t) == 30)      WAITN(6);                                        \
    else if ((t) == 31)      WAITN(0);                                        \
    else if (((t) & 1) || (t) == 2 || (t) == 28) WAITN(22);                   \
    else                     WAITN(26);                                       \
    {                                                                         \
        const char* xb = wbase + (((t) >> 1) % 3) * 4096;                     \
        const float4 a0 = *(const float4*)(xb + r31 * 128 +                   \
            (((((t) & 1) * 4 + 2 * l5 + 0) ^ swr) << 4));                     \
        const float4 a1 = *(const float4*)(xb + r31 * 128 +                   \
            (((((t) & 1) * 4 + 2 * l5 + 1) ^ swr) << 4));                     \
        short8 H, M, L;                                                       \
        split3(a0, a1, H, M, L);                                              \
        acc0 = mfma6w(H, M, L, as_s8(w0v[(t)&3][0]), as_s8(w0v[(t)&3][1]),    \
                      as_s8(w0v[(t)&3][2]), acc0);                            \
        acc1 = mfma6w(H, M, L, as_s8(w1v[(t)&3][0]), as_s8(w1v[(t)&3][1]),    \
                      as_s8(w1v[(t)&3][2]), acc1);                            \
    }                                                                         \
    if (((t) & 1) && (t) <= 25) STAGE_CHUNK(((t) + 5) >> 1);                  \
} while (0)

    SLICE(0);  SLICE(1);  SLICE(2);  SLICE(3);
    SLICE(4);  SLICE(5);  SLICE(6);  SLICE(7);
    SLICE(8);  SLICE(9);  SLICE(10); SLICE(11);
    SLICE(12); SLICE(13); SLICE(14); SLICE(15);
    SLICE(16); SLICE(17); SLICE(18); SLICE(19);
    SLICE(20); SLICE(21); SLICE(22); SLICE(23);
    SLICE(24); SLICE(25); SLICE(26); SLICE(27);
    SLICE(28); SLICE(29); SLICE(30); SLICE(31);

    // ---- all waves done (lg aliases staging buffers) ----
    __syncthreads();

    // partials -> lg[kq][64][65]; C/D 32x32: col=l&31, row=(r&3)+8*(r>>2)+4*l5
    float* lg = (float*)smem;
#pragma unroll
    for (int r = 0; r < 16; ++r) {
        const int rowc = (r & 3) + 8 * (r >> 2) + 4 * l5;
        const int trow = 32 * tw + rowc;
        lg[(kq * TT + trow) * (NE + 1) + r31]      = acc0[r];
        lg[(kq * TT + trow) * (NE + 1) + 32 + r31] = acc1[r];
    }
    __syncthreads();

    // ---- deterministic 4-way K-split reduction: 4096 entries / 512 thr ----
#pragma unroll
    for (int rr = 0; rr < (TT * NE) / 512; ++rr) {
        const int idx = tid + rr * 512;
        const int t = idx >> 6, e = idx & 63;
        lg[t * (NE + 1) + e] =
            (lg[t * (NE + 1) + e] + lg[(TT + t) * (NE + 1) + e]) +
            (lg[(2 * TT + t) * (NE + 1) + e] + lg[(3 * TT + t) * (NE + 1) + e]);
    }
    __syncthreads();

    // ---- fused softmax + top-8: one lane per token ----
    if (tid < TT) {
        const float* rowp = lg + tid * (NE + 1);
        float mx = -3.402823466e38f;
        for (int e = 0; e < NE; ++e) mx = fmaxf(mx, rowp[e]);
        float sden = 0.f;
        for (int e = 0; e < NE; ++e) sden += expf(rowp[e] - mx);

        float tv[TOPKK];
        int   ti[TOPKK];
#pragma unroll
        for (int i = 0; i < TOPKK; ++i) { tv[i] = -3.402823466e38f; ti[i] = 0; }
        for (int e = 0; e < NE; ++e) {
            const float v = rowp[e];
            if (v > tv[TOPKK - 1]) {
                tv[TOPKK - 1] = v; ti[TOPKK - 1] = e;
#pragma unroll
                for (int q = TOPKK - 1; q > 0; --q) {
                    if (tv[q] > tv[q - 1]) {
                        const float fv = tv[q]; tv[q] = tv[q - 1]; tv[q - 1] = fv;
                        const int   iv = ti[q]; ti[q] = ti[q - 1]; ti[q - 1] = iv;
                    }
                }
            }
        }
        float* ow = out + (size_t)(bt0 + tid) * TOPKK;
        float* oi = out + (size_t)NT * TOPKK + (size_t)(bt0 + tid) * TOPKK;
#pragma unroll
        for (int i = 0; i < TOPKK; ++i) {
            ow[i] = expf(tv[i] - mx) / sden;   // ROUTE_SCALE == 1.0
            oi[i] = (float)ti[i];
        }
    }
#undef SLICE
#undef STAGE_CHUNK
}

// ================= fallback (R2 kernel) if ws too small =================
__device__ __forceinline__ f32x4 mfma6s(short8 ah, short8 am, short8 al,
                                        short8 bh, short8 bm, short8 bl, f32x4 c) {
    c = __builtin_amdgcn_mfma_f32_16x16x32_bf16(ah, bh, c, 0, 0, 0);
    c = __builtin_amdgcn_mfma_f32_16x16x32_bf16(ah, bm, c, 0, 0, 0);
    c = __builtin_amdgcn_mfma_f32_16x16x32_bf16(am, bh, c, 0, 0, 0);
    c = __builtin_amdgcn_mfma_f32_16x16x32_bf16(ah, bl, c, 0, 0, 0);
    c = __builtin_amdgcn_mfma_f32_16x16x32_bf16(am, bm, c, 0, 0, 0);
    c = __builtin_amdgcn_mfma_f32_16x16x32_bf16(al, bh, c, 0, 0, 0);
    return c;
}

__device__ __forceinline__ void load_step(const float* xp0, const float* xp1,
                                          const float* wp, int koff,
                                          float4 xb[2][2], float4 wb[4][2]) {
#pragma unroll
    for (int h = 0; h < 2; ++h) {
        xb[0][h] = *(const float4*)(xp0 + koff + 4 * h);
        xb[1][h] = *(const float4*)(xp1 + koff + 4 * h);
    }
#pragma unroll
    for (int n = 0; n < 4; ++n)
#pragma unroll
        for (int h = 0; h < 2; ++h)
            wb[n][h] = *(const float4*)(wp + (size_t)n * 16 * DIMK + koff + 4 * h);
}

__device__ __forceinline__ void do_step(const float4 xc[2][2], const float4 wc[4][2],
                                        f32x4 acc[2][4]) {
    short8 ah[2], am[2], al[2];
#pragma unroll
    for (int m = 0; m < 2; ++m) split3(xc[m][0], xc[m][1], ah[m], am[m], al[m]);
#pragma unroll
    for (int n = 0; n < 4; ++n) {
        short8 bh, bm, bl;
        split3(wc[n][0], wc[n][1], bh, bm, bl);
#pragma unroll
        for (int m = 0; m < 2; ++m)
            acc[m][n] = mfma6s(ah[m], am[m], al[m], bh, bm, bl, acc[m][n]);
    }
}

__global__ __launch_bounds__(256, 2) void gate_fallback_kernel(
    const float* __restrict__ x, const float* __restrict__ W,
    float* __restrict__ out)
{
    __shared__ float lg[4][32][NE + 1];
    const int tid = threadIdx.x;
    const int w = tid >> 6, l = tid & 63;
    const int j = l & 15, g = l >> 4;
    const int bt0 = blockIdx.x * 32;
    const int kb = w * 512;
    const float* xp0 = x + (size_t)(bt0 + j) * DIMK + kb + 8 * g;
    const float* xp1 = xp0 + (size_t)16 * DIMK;
    const float* wpp = W + (size_t)j * DIMK + kb + 8 * g;
    f32x4 acc[2][4];
#pragma unroll
    for (int m = 0; m < 2; ++m)
#pragma unroll
        for (int n = 0; n < 4; ++n) acc[m][n] = (f32x4){0.f, 0.f, 0.f, 0.f};
    float4 xA[2][2], wA[4][2], xB[2][2], wB[4][2];
    load_step(xp0, xp1, wpp, 0, xA, wA);
#pragma unroll 1
    for (int s = 0; s < 16; s += 2) {
        load_step(xp0, xp1, wpp, 32 * (s + 1), xB, wB);
        do_step(xA, wA, acc);
        if (s + 2 < 16) load_step(xp0, xp1, wpp, 32 * (s + 2), xA, wA);
        do_step(xB, wB, acc);
    }
#pragma unroll
    for (int m = 0; m < 2; ++m)
#pragma unroll
        for (int n = 0; n < 4; ++n)
#pragma unroll
            for (int q = 0; q < 4; ++q)
                lg[w][16 * m + 4 * g + q][16 * n + j] = acc[m][n][q];
    __syncthreads();
#pragma unroll
    for (int r = 0; r < 8; ++r) {
        const int idx = tid + r * 256;
        const int t = idx >> 6, e = idx & 63;
        lg[0][t][e] += lg[1][t][e] + lg[2][t][e] + lg[3][t][e];
    }
    __syncthreads();
    if (tid < 32) {
        const float* rowp = &lg[0][tid][0];
        float mx = -3.402823466e38f;
        for (int e = 0; e < NE; ++e) mx = fmaxf(mx, rowp[e]);
        float sden = 0.f;
        for (int e = 0; e < NE; ++e) sden += expf(rowp[e] - mx);
        float tv[TOPKK]; int ti[TOPKK];
#pragma unroll
        for (int i = 0; i < TOPKK; ++i) { tv[i] = -3.402823466e38f; ti[i] = 0; }
        for (int e = 0; e < NE; ++e) {
            const float v = rowp[e];
            if (v > tv[TOPKK - 1]) {
                tv[TOPKK - 1] = v; ti[TOPKK - 1] = e;
#pragma unroll
                for (int q = TOPKK - 1; q > 0; --q)
                    if (tv[q] > tv[q - 1]) {
                        const float fv = tv[q]; tv[q] = tv[q - 1]; tv[q - 1] = fv;
                        const int iv = ti[q]; ti[q] = ti[q - 1]; ti[q - 1] = iv;
                    }
            }
        }
        float* ow = out + (size_t)(bt0 + tid) * TOPKK;
        float* oi = out + (size_t)NT * TOPKK + (size_t)(bt0 + tid) * TOPKK;
#pragma unroll
        for (int i = 0; i < TOPKK; ++i) {
            ow[i] = expf(tv[i] - mx) / sden;
            oi[i] = (float)ti[i];
        }
    }
}

extern "C" void kernel_launch(void* const* d_in, const int* in_sizes, int n_in,
                              void* d_out, int out_size, void* d_ws, size_t ws_size,
                              hipStream_t stream) {
    const float* x = (const float*)d_in[0];
    const float* W = (const float*)d_in[1];
    float* out = (float*)d_out;
    if (ws_size >= (size_t)WS_BYTES) {
        short* wpk = (short*)d_ws;
        hipLaunchKernelGGL(pack_w_kernel, dim3(256), dim3(64), 0, stream, W, wpk);
        hipLaunchKernelGGL(gate_main_kernel, dim3(NT / TT), dim3(512), 0, stream,
                           x, wpk, out);
    } else {
        hipLaunchKernelGGL(gate_fallback_kernel, dim3(NT / 32), dim3(256), 0, stream,
                           x, W, out);
    }
}